// Round 2
// baseline (2131.689 us; speedup 1.0000x reference)
//
#include <hip/hip_runtime.h>

// CrossNetMix fused kernel: B=16384, D=1024, L=3, E=4, R=64, fp32.
// One block = 32 rows through all 3 layers. d_out serves as the x_l buffer.
// Regime: VALU-bound fp32 (no fp32 MFMA on CDNA4). Floor ~342us at 157TF.

#define TB   32      // rows per block
#define DIM  1024    // D
#define RR   64      // R
#define NE   4       // experts
#define NL   3       // layers
#define N1   256     // E*R
#define KC1  32      // GEMM1 K-chunk
#define KC2  32      // GEMM2 K-chunk
#define NC2  128     // GEMM2 N-chunk

struct SM {
  union {
    struct {                       // GEMM1 staging
      float As[KC1][TB + 4];       // [k][row], stride 36 floats (144B, 16B-aligned)
      float Bs[KC1][N1 + 4];       // [k][col], stride 260 floats (1040B, 16B-aligned)
    } g1;
    struct {                       // phase-2/3 buffers
      float vbuf[TB][N1 + 4];      // [row][col]: v after GEMM1, then w = gate*tanh(c)
      float Us[KC2][NC2 + 4];      // [k][n], stride 132 floats (528B, 16B-aligned)
    } g2;
  } u;
  float gp[TB][NE][2];             // gate partial dots
  float gate[TB][NE];              // softmaxed gates
};

__global__ __launch_bounds__(256, 2)
void crossnet_kernel(const float* __restrict__ x,
                     const float* __restrict__ Uw,    // (L,E,D,R)
                     const float* __restrict__ Vw,    // (L,E,D,R)
                     const float* __restrict__ Cw,    // (L,E,R,R)
                     const float* __restrict__ bias,  // (L,D)
                     const float* __restrict__ G,     // (E,D)
                     float* __restrict__ out)         // (B,D): x_l buffer + final out
{
  __shared__ SM sm;
  const int t  = threadIdx.x;
  const int tc = t & 31;   // 0..31 (col group)
  const int tr = t >> 5;   // 0..7  (row group)
  const int b0 = blockIdx.x * TB;

  for (int layer = 0; layer < NL; ++layer) {
    const float* xin = (layer == 0) ? x : out;
    __syncthreads();   // order prev-layer global writes vs this layer's reads

    // ---------------- gate pass: gp[b][e] = G[e,:] . x_l[b,:] ----------------
    {
      const int gb = t >> 3;        // 0..31 row
      const int ge = (t >> 1) & 3;  // 0..3 expert
      const int gh = t & 1;         // half
      const float4* xr = reinterpret_cast<const float4*>(xin + (size_t)(b0 + gb) * DIM) + gh * 128;
      const float4* gr = reinterpret_cast<const float4*>(G + (size_t)ge * DIM) + gh * 128;
      float s = 0.f;
      for (int q = 0; q < 128; ++q) {
        float4 a = xr[q], g4 = gr[q];
        s += a.x * g4.x + a.y * g4.y + a.z * g4.z + a.w * g4.w;
      }
      sm.gp[gb][ge][gh] = s;
    }
    __syncthreads();
    if (t < TB) {                   // softmax over experts for row t
      float z[NE];
      float m = -1e30f;
      #pragma unroll
      for (int e = 0; e < NE; ++e) { z[e] = sm.gp[t][e][0] + sm.gp[t][e][1]; m = fmaxf(m, z[e]); }
      float den = 0.f;
      #pragma unroll
      for (int e = 0; e < NE; ++e) { z[e] = expf(z[e] - m); den += z[e]; }
      const float inv = 1.f / den;
      #pragma unroll
      for (int e = 0; e < NE; ++e) sm.gate[t][e] = z[e] * inv;
    }

    // ---------------- GEMM1: v_pre(32x256) = x_tile(32x1024) @ V'(1024x256) ----------------
    float acc[4][8];
    #pragma unroll
    for (int r2 = 0; r2 < 4; ++r2)
      #pragma unroll
      for (int j = 0; j < 8; ++j) acc[r2][j] = 0.f;

    for (int kc = 0; kc < DIM / KC1; ++kc) {
      __syncthreads();   // guards gate_lds writes (iter 0) / prior chunk reads
      {  // stage A transposed: As[k][r]
        const int r = t >> 3, kq = t & 7;
        const float4 a4 = *reinterpret_cast<const float4*>(
            xin + (size_t)(b0 + r) * DIM + kc * KC1 + kq * 4);
        sm.u.g1.As[kq * 4 + 0][r] = a4.x;
        sm.u.g1.As[kq * 4 + 1][r] = a4.y;
        sm.u.g1.As[kq * 4 + 2][r] = a4.z;
        sm.u.g1.As[kq * 4 + 3][r] = a4.w;
      }
      #pragma unroll
      for (int j = 0; j < 8; ++j) {  // stage B: Bs[k][col] = V[layer,e,kglob,r]
        const int p = j * 256 + t;
        const int k = p >> 6;              // 0..31
        const int col = (p & 63) * 4;      // 0..252
        const int e = col >> 6, r = col & 63;
        const float4 b4 = *reinterpret_cast<const float4*>(
            Vw + (((size_t)layer * NE + e) * DIM + (size_t)(kc * KC1 + k)) * RR + r);
        *reinterpret_cast<float4*>(&sm.u.g1.Bs[k][col]) = b4;
      }
      __syncthreads();
      #pragma unroll 8
      for (int k = 0; k < KC1; ++k) {
        const float4 av  = *reinterpret_cast<const float4*>(&sm.u.g1.As[k][tr * 4]);
        const float4 bv0 = *reinterpret_cast<const float4*>(&sm.u.g1.Bs[k][tc * 4]);
        const float4 bv1 = *reinterpret_cast<const float4*>(&sm.u.g1.Bs[k][128 + tc * 4]);
        const float aa[4] = {av.x, av.y, av.z, av.w};
        const float bb[8] = {bv0.x, bv0.y, bv0.z, bv0.w, bv1.x, bv1.y, bv1.z, bv1.w};
        #pragma unroll
        for (int r2 = 0; r2 < 4; ++r2)
          #pragma unroll
          for (int j = 0; j < 8; ++j)
            acc[r2][j] = fmaf(aa[r2], bb[j], acc[r2][j]);
      }
    }
    __syncthreads();   // all Bs/As reads done -> safe to overwrite union with vbuf

    // v = tanh(v_pre) -> vbuf
    #pragma unroll
    for (int r2 = 0; r2 < 4; ++r2) {
      const int b = tr * 4 + r2;
      #pragma unroll
      for (int g = 0; g < 2; ++g) {
        float4 w4;
        w4.x = tanhf(acc[r2][g * 4 + 0]);
        w4.y = tanhf(acc[r2][g * 4 + 1]);
        w4.z = tanhf(acc[r2][g * 4 + 2]);
        w4.w = tanhf(acc[r2][g * 4 + 3]);
        *reinterpret_cast<float4*>(&sm.u.g2.vbuf[b][g * 128 + tc * 4]) = w4;
      }
    }
    __syncthreads();

    // ---------------- C-step: c[b][e,r] = sum_s C[l,e,r,s] * v[b][e,s] ----------------
    float cacc[4][8];
    #pragma unroll
    for (int r2 = 0; r2 < 4; ++r2)
      #pragma unroll
      for (int j = 0; j < 8; ++j) cacc[r2][j] = 0.f;

    #pragma unroll
    for (int g = 0; g < 2; ++g) {
      const int colbase = g * 128 + tc * 4;
      const int e = colbase >> 6;
      const int rbase = colbase & 63;
      const float* Crow = Cw + ((size_t)layer * NE + e) * RR * RR;
      for (int s4 = 0; s4 < 16; ++s4) {
        float4 v4[4];
        #pragma unroll
        for (int r2 = 0; r2 < 4; ++r2)
          v4[r2] = *reinterpret_cast<const float4*>(&sm.u.g2.vbuf[tr * 4 + r2][e * 64 + s4 * 4]);
        #pragma unroll
        for (int j = 0; j < 4; ++j) {
          const float4 c4 = *reinterpret_cast<const float4*>(Crow + (size_t)(rbase + j) * RR + s4 * 4);
          #pragma unroll
          for (int r2 = 0; r2 < 4; ++r2)
            cacc[r2][g * 4 + j] += c4.x * v4[r2].x + c4.y * v4[r2].y +
                                   c4.z * v4[r2].z + c4.w * v4[r2].w;
        }
      }
    }
    __syncthreads();   // all v reads done -> safe to overwrite vbuf with w

    // w = gate * tanh(c) -> vbuf
    #pragma unroll
    for (int g = 0; g < 2; ++g) {
      const int colbase = g * 128 + tc * 4;
      const int e = colbase >> 6;
      #pragma unroll
      for (int r2 = 0; r2 < 4; ++r2) {
        const int b = tr * 4 + r2;
        const float gt = sm.gate[b][e];
        float4 w4;
        w4.x = gt * tanhf(cacc[r2][g * 4 + 0]);
        w4.y = gt * tanhf(cacc[r2][g * 4 + 1]);
        w4.z = gt * tanhf(cacc[r2][g * 4 + 2]);
        w4.w = gt * tanhf(cacc[r2][g * 4 + 3]);
        *reinterpret_cast<float4*>(&sm.u.g2.vbuf[b][colbase]) = w4;
      }
    }

    // ---------------- GEMM2 + combine: ubar(32x1024) = w(32x256) @ U'(256x1024) ----------------
    for (int nc = 0; nc < DIM / NC2; ++nc) {
      float acc2[4][4];
      #pragma unroll
      for (int r2 = 0; r2 < 4; ++r2)
        #pragma unroll
        for (int j = 0; j < 4; ++j) acc2[r2][j] = 0.f;

      for (int kc2 = 0; kc2 < N1 / KC2; ++kc2) {
        const int e  = kc2 >> 1;
        const int rb = (kc2 & 1) * 32;
        __syncthreads();   // guards w writes (iter 0) / prior Us reads
        #pragma unroll
        for (int j = 0; j < 4; ++j) {   // stage Us[k][n] = U[layer,e,d,rb+k]
          const int p = j * 256 + t;
          const int n = p >> 3;         // 0..127
          const int kq = p & 7;         // k = kq*4 ..
          const float4 u4 = *reinterpret_cast<const float4*>(
              Uw + (((size_t)layer * NE + e) * DIM + (size_t)(nc * NC2 + n)) * RR + rb + kq * 4);
          sm.u.g2.Us[kq * 4 + 0][n] = u4.x;
          sm.u.g2.Us[kq * 4 + 1][n] = u4.y;
          sm.u.g2.Us[kq * 4 + 2][n] = u4.z;
          sm.u.g2.Us[kq * 4 + 3][n] = u4.w;
        }
        __syncthreads();
        #pragma unroll
        for (int k4 = 0; k4 < KC2 / 4; ++k4) {
          float wv[4][4];
          #pragma unroll
          for (int r2 = 0; r2 < 4; ++r2) {
            const float4 wq = *reinterpret_cast<const float4*>(
                &sm.u.g2.vbuf[tr * 4 + r2][kc2 * KC2 + k4 * 4]);
            wv[r2][0] = wq.x; wv[r2][1] = wq.y; wv[r2][2] = wq.z; wv[r2][3] = wq.w;
          }
          #pragma unroll
          for (int kk = 0; kk < 4; ++kk) {
            const float4 u4 = *reinterpret_cast<const float4*>(&sm.u.g2.Us[k4 * 4 + kk][tc * 4]);
            const float uu[4] = {u4.x, u4.y, u4.z, u4.w};
            #pragma unroll
            for (int r2 = 0; r2 < 4; ++r2)
              #pragma unroll
              for (int j = 0; j < 4; ++j)
                acc2[r2][j] = fmaf(wv[r2][kk], uu[j], acc2[r2][j]);
          }
        }
      }
      // combine: x_l_new = x0 * (ubar + bias) + x_l   (softmax gates sum to 1)
      const int d0 = nc * NC2 + tc * 4;
      const float4 bv = *reinterpret_cast<const float4*>(bias + (size_t)layer * DIM + d0);
      #pragma unroll
      for (int r2 = 0; r2 < 4; ++r2) {
        const size_t off = (size_t)(b0 + tr * 4 + r2) * DIM + d0;
        const float4 x0v = *reinterpret_cast<const float4*>(x + off);
        const float4 xlv = *reinterpret_cast<const float4*>(xin + off);
        float4 o;
        o.x = x0v.x * (acc2[r2][0] + bv.x) + xlv.x;
        o.y = x0v.y * (acc2[r2][1] + bv.y) + xlv.y;
        o.z = x0v.z * (acc2[r2][2] + bv.z) + xlv.z;
        o.w = x0v.w * (acc2[r2][3] + bv.w) + xlv.w;
        *reinterpret_cast<float4*>(out + off) = o;
      }
    }
  }
}

extern "C" void kernel_launch(void* const* d_in, const int* in_sizes, int n_in,
                              void* d_out, int out_size, void* d_ws, size_t ws_size,
                              hipStream_t stream) {
  const float* x    = (const float*)d_in[0];
  const float* Uw   = (const float*)d_in[1];
  const float* Vw   = (const float*)d_in[2];
  const float* Cw   = (const float*)d_in[3];
  const float* bias = (const float*)d_in[4];
  const float* G    = (const float*)d_in[5];
  float* out = (float*)d_out;

  const int B = in_sizes[0] / DIM;   // 16384
  dim3 grid(B / TB), block(256);
  hipLaunchKernelGGL(crossnet_kernel, grid, block, 0, stream,
                     x, Uw, Vw, Cw, bias, G, out);
}